// Round 10
// baseline (228.263 us; speedup 1.0000x reference)
//
#include <hip/hip_runtime.h>

#define NNODES 50000
#define NEDGES 800000
#define ETOT   (NNODES + NEDGES)   // 850000 (edges + self loops)
#define NEG 0.2f
#define BKTS 196                   // coarse buckets of 256 nodes (49999>>8 = 195)
#define P1E 4096                   // edges per phase-1 block
#define NP1 ((ETOT + P1E - 1) / P1E)   // 208
#define GEMM1_NB ((NNODES + 31) / 32)  // 1563
#define GEMM1_H1 782
#define GEMM1_H2 (GEMM1_NB - GEMM1_H1) // 781

typedef unsigned short ushort_t;
typedef unsigned int uint_t;
typedef __attribute__((ext_vector_type(8))) short short8;   // 8 bf16 (4 VGPRs)
typedef __attribute__((ext_vector_type(4))) float f32x4;    // 4 fp32 acc
typedef __attribute__((ext_vector_type(2))) float f32x2;    // packed fp32 pair (VOP3P)

__device__ __forceinline__ ushort_t f2bf(float f) {   // RTN bf16
  uint_t u = __float_as_uint(f);
  u += 0x7FFFu + ((u >> 16) & 1u);
  return (ushort_t)(u >> 16);
}
__device__ __forceinline__ float bf2f(ushort_t h) {
  return __uint_as_float((uint_t)h << 16);
}
__device__ __forceinline__ f32x2 unpk2(uint_t u) {    // 2 bf16 -> f32x2
  f32x2 r;
  r.x = __uint_as_float(u << 16);
  r.y = __uint_as_float(u & 0xffff0000u);
  return r;
}

// ================= device bodies (fused below) =================

__device__ __forceinline__ void coarse_hist_body(int bid, int tid,
    const int* __restrict__ ei, int* __restrict__ pcnt, int* c /*BKTS in LDS*/) {
  for (int i = tid; i < BKTS; i += 256) c[i] = 0;
  __syncthreads();
  int e0 = bid * P1E;
#pragma unroll
  for (int t = 0; t < P1E / 256; ++t) {
    int i = e0 + t * 256 + tid;
    if (i < ETOT) {
      int dst = (i < NEDGES) ? ei[NEDGES + i] : (i - NEDGES);
      atomicAdd(&c[dst >> 8], 1);
    }
  }
  __syncthreads();
  for (int i = tid; i < BKTS; i += 256)
    pcnt[i * NP1 + bid] = c[i];
}

__device__ __forceinline__ void prep_w_body(int k, int n,
    const float* __restrict__ Wl1, const float* __restrict__ Wr1,
    ushort_t* __restrict__ WtHi, ushort_t* __restrict__ WtLo) {
  float w = (n < 128) ? Wl1[k * 128 + n] : Wr1[k * 128 + (n - 128)];
  ushort_t h = f2bf(w);
  WtHi[n * 128 + k] = h;
  WtLo[n * 128 + k] = f2bf(w - bf2f(h));
}

// W2 transpose + split-bf16: [64 concat cols][128 k]
__device__ __forceinline__ void prep_w2_body(int e,
    const float* __restrict__ Wl2, const float* __restrict__ Wr2,
    ushort_t* __restrict__ Wt2Hi, ushort_t* __restrict__ Wt2Lo) {
  int k = e & 127, n = e >> 7;     // e < 8192
  float w = (n < 32) ? Wl2[k * 32 + n] : Wr2[k * 32 + (n - 32)];
  ushort_t hh = f2bf(w);
  Wt2Hi[n * 128 + k] = hh;
  Wt2Lo[n * 128 + k] = f2bf(w - bf2f(hh));
}

__device__ __forceinline__ void bin1_body(int bid, int tid,
    const int* __restrict__ ei, const int* __restrict__ bucketStart,
    const int* __restrict__ goffArr, uint_t* __restrict__ binned, char* smemc) {
  int* cnt   = (int*)smemc;        // BKTS
  int* pref  = cnt + BKTS;
  int* fillL = pref + BKTS;
  uint_t* stage = (uint_t*)(fillL + BKTS);   // P1E
  int e0 = bid * P1E;
  for (int i = tid; i < BKTS; i += 256) { cnt[i] = 0; fillL[i] = 0; }
  __syncthreads();
  uint_t mypk[P1E / 256];
#pragma unroll
  for (int t = 0; t < P1E / 256; ++t) {
    int i = e0 + t * 256 + tid;
    if (i < ETOT) {
      int dst = (i < NEDGES) ? ei[NEDGES + i] : (i - NEDGES);
      int src = (i < NEDGES) ? ei[i] : dst;
      int b = dst >> 8;
      mypk[t] = (uint_t)src | ((uint_t)(dst & 255) << 16) | ((uint_t)b << 24);
      atomicAdd(&cnt[b], 1);
    } else mypk[t] = 0xFFFFFFFFu;   // b=255 >= BKTS -> skipped
  }
  __syncthreads();
  if (tid < 64) {                  // wave-0 exclusive scan of cnt -> pref
    int carry = 0;
    for (int k0 = 0; k0 < BKTS; k0 += 64) {
      int k = k0 + tid;
      int v = (k < BKTS) ? cnt[k] : 0;
      int s = v;
      for (int off = 1; off < 64; off <<= 1) {
        int u = __shfl_up(s, off);
        if (tid >= off) s += u;
      }
      if (k < BKTS) pref[k] = carry + s - v;
      carry += __shfl(s, 63);
    }
  }
  __syncthreads();
#pragma unroll
  for (int t = 0; t < P1E / 256; ++t) {
    uint_t pk = mypk[t];
    int b = pk >> 24;
    if (b < BKTS) {
      int p = pref[b] + atomicAdd(&fillL[b], 1);
      stage[p] = pk;
    }
  }
  __syncthreads();
  int total = (e0 + P1E <= ETOT) ? P1E : (ETOT - e0);
  for (int j = tid; j < total; j += 256) {
    uint_t pk = stage[j];
    int b = pk >> 24;
    binned[bucketStart[b] + goffArr[b * NP1 + bid] + (j - pref[b])] = pk;
  }
}

__device__ __forceinline__ void bin2_body(int b, int tid,
    const uint_t* __restrict__ binned, const int* __restrict__ bucketStart,
    int* __restrict__ rowptr, int* __restrict__ csrc, char* smemc) {
  int* cnt   = (int*)smemc;        // 256
  int* pref  = cnt + 256;
  int* fillL = pref + 256;
  int* outS  = fillL + 256;        // up to 7424 ints within 33280-B union
  int base = bucketStart[b];
  int cntAll = bucketStart[b + 1] - base;
  cnt[tid] = 0; fillL[tid] = 0;
  __syncthreads();
  for (int j = tid; j < cntAll; j += 256)
    atomicAdd(&cnt[(binned[base + j] >> 16) & 255], 1);
  __syncthreads();
  if (tid < 64) {                  // wave-0 exclusive scan of 256 counts
    int carry = 0;
    for (int k0 = 0; k0 < 256; k0 += 64) {
      int k = k0 + tid;
      int v = cnt[k];
      int s = v;
      for (int off = 1; off < 64; off <<= 1) {
        int u = __shfl_up(s, off);
        if (tid >= off) s += u;
      }
      pref[k] = carry + s - v;
      carry += __shfl(s, 63);
    }
  }
  __syncthreads();
  int node = b * 256 + tid;
  if (node < NNODES) rowptr[node] = base + pref[tid];
  for (int j = tid; j < cntAll; j += 256) {
    uint_t pk = binned[base + j];
    int d = (pk >> 16) & 255;
    int p = pref[d] + atomicAdd(&fillL[d], 1);
    outS[p] = (int)(pk & 0xFFFF);
  }
  __syncthreads();
  for (int j = tid; j < cntAll; j += 256)
    csrc[base + j] = outS[j];
}

// GEMM1 body via MFMA (split-bf16 = fp32-quality); round-0/5 proven structure
// (single-pass Cs[32][260] epilogue).
__device__ __forceinline__ void gemm1_body(int m0, int tid,
    const float* __restrict__ x,
    const ushort_t* __restrict__ WtHi, const ushort_t* __restrict__ WtLo,
    const float* __restrict__ bl1, const float* __restrict__ br1,
    ushort_t* __restrict__ gl1, ushort_t* __restrict__ gr1, char* smem) {
  constexpr int LDA = 132;
  ushort_t (*Ahi)[LDA] = (ushort_t(*)[LDA])smem;
  ushort_t (*Alo)[LDA] = (ushort_t(*)[LDA])(smem + 32 * LDA * 2);
  float (*Cs)[260] = (float(*)[260])smem;   // overlays Ahi/Alo after compute
#pragma unroll
  for (int i = 0; i < 4; ++i) {
    int it = i * 256 + tid;
    int row = it >> 5, c4 = it & 31;
    int gm = m0 + row;
    float4 v = (gm < NNODES) ? *(const float4*)&x[(size_t)gm * 128 + 4 * c4]
                             : make_float4(0.f, 0.f, 0.f, 0.f);
    ushort_t h0 = f2bf(v.x), h1 = f2bf(v.y), h2 = f2bf(v.z), h3 = f2bf(v.w);
    ushort_t l0 = f2bf(v.x - bf2f(h0)), l1 = f2bf(v.y - bf2f(h1));
    ushort_t l2 = f2bf(v.z - bf2f(h2)), l3 = f2bf(v.w - bf2f(h3));
    uint2 ph, pl;
    ph.x = (uint_t)h0 | ((uint_t)h1 << 16); ph.y = (uint_t)h2 | ((uint_t)h3 << 16);
    pl.x = (uint_t)l0 | ((uint_t)l1 << 16); pl.y = (uint_t)l2 | ((uint_t)l3 << 16);
    *(uint2*)&Ahi[row][4 * c4] = ph;
    *(uint2*)&Alo[row][4 * c4] = pl;
  }
  __syncthreads();
  int wave = tid >> 6, lane = tid & 63;
  int quad = lane >> 4, nl = lane & 15;
  int nb = wave * 64;
  f32x4 acc[2][4];
#pragma unroll
  for (int tm = 0; tm < 2; ++tm)
#pragma unroll
    for (int tn = 0; tn < 4; ++tn) acc[tm][tn] = (f32x4){0.f, 0.f, 0.f, 0.f};

#pragma unroll
  for (int kc = 0; kc < 4; ++kc) {
    int klane = kc * 32 + quad * 8;
    short8 ah[2], al[2], bh[4], bl[4];
#pragma unroll
    for (int tm = 0; tm < 2; ++tm) {
      ah[tm] = *(const short8*)&Ahi[16 * tm + nl][klane];
      al[tm] = *(const short8*)&Alo[16 * tm + nl][klane];
    }
#pragma unroll
    for (int tn = 0; tn < 4; ++tn) {
      size_t wo = (size_t)(nb + 16 * tn + nl) * 128 + klane;
      bh[tn] = *(const short8*)&WtHi[wo];
      bl[tn] = *(const short8*)&WtLo[wo];
    }
#pragma unroll
    for (int tm = 0; tm < 2; ++tm)
#pragma unroll
      for (int tn = 0; tn < 4; ++tn) {
        acc[tm][tn] = __builtin_amdgcn_mfma_f32_16x16x32_bf16(ah[tm], bh[tn], acc[tm][tn], 0, 0, 0);
        acc[tm][tn] = __builtin_amdgcn_mfma_f32_16x16x32_bf16(ah[tm], bl[tn], acc[tm][tn], 0, 0, 0);
        acc[tm][tn] = __builtin_amdgcn_mfma_f32_16x16x32_bf16(al[tm], bh[tn], acc[tm][tn], 0, 0, 0);
      }
  }
  float bb[4];
#pragma unroll
  for (int tn = 0; tn < 4; ++tn) {
    int n = nb + 16 * tn + nl;
    bb[tn] = (n < 128) ? bl1[n] : br1[n - 128];
  }
  __syncthreads();   // all A-tile reads done before Cs overlays the same LDS
#pragma unroll
  for (int tm = 0; tm < 2; ++tm)
#pragma unroll
    for (int tn = 0; tn < 4; ++tn)
#pragma unroll
      for (int r = 0; r < 4; ++r)
        Cs[16 * tm + 4 * quad + r][nb + 16 * tn + nl] = acc[tm][tn][r] + bb[tn];
  __syncthreads();
#pragma unroll
  for (int i = 0; i < 2; ++i) {     // gl1 (cols 0..127, bf16)
    int it = i * 256 + tid;
    int row = it >> 4, oc = (it & 15) * 8;
    int gm = m0 + row;
    if (gm < NNODES) {
      uint4 pk;
      pk.x = (uint_t)f2bf(Cs[row][oc + 0]) | ((uint_t)f2bf(Cs[row][oc + 1]) << 16);
      pk.y = (uint_t)f2bf(Cs[row][oc + 2]) | ((uint_t)f2bf(Cs[row][oc + 3]) << 16);
      pk.z = (uint_t)f2bf(Cs[row][oc + 4]) | ((uint_t)f2bf(Cs[row][oc + 5]) << 16);
      pk.w = (uint_t)f2bf(Cs[row][oc + 6]) | ((uint_t)f2bf(Cs[row][oc + 7]) << 16);
      *(uint4*)&gl1[(size_t)gm * 128 + oc] = pk;
    }
  }
#pragma unroll
  for (int i = 0; i < 2; ++i) {     // gr1 (cols 128..255, bf16)
    int it = i * 256 + tid;
    int row = it >> 4, oc = (it & 15) * 8;
    int gm = m0 + row;
    if (gm < NNODES) {
      uint4 pk;
      pk.x = (uint_t)f2bf(Cs[row][128 + oc + 0]) | ((uint_t)f2bf(Cs[row][128 + oc + 1]) << 16);
      pk.y = (uint_t)f2bf(Cs[row][128 + oc + 2]) | ((uint_t)f2bf(Cs[row][128 + oc + 3]) << 16);
      pk.z = (uint_t)f2bf(Cs[row][128 + oc + 4]) | ((uint_t)f2bf(Cs[row][128 + oc + 5]) << 16);
      pk.w = (uint_t)f2bf(Cs[row][128 + oc + 6]) | ((uint_t)f2bf(Cs[row][128 + oc + 7]) << 16);
      *(uint4*)&gr1[(size_t)gm * 128 + oc] = pk;
    }
  }
}

// ================= fused kernels =================

// coarse_hist (0..NP1-1) || prep_w (NP1..NP1+127) || prep_w2 (NP1+128..NP1+159)
__global__ __launch_bounds__(256) void fusedA(const int* __restrict__ ei,
    int* __restrict__ pcnt,
    const float* __restrict__ Wl1, const float* __restrict__ Wr1,
    ushort_t* __restrict__ WtHi, ushort_t* __restrict__ WtLo,
    const float* __restrict__ Wl2, const float* __restrict__ Wr2,
    ushort_t* __restrict__ Wt2Hi, ushort_t* __restrict__ Wt2Lo,
    int* __restrict__ done) {
  __shared__ int c[BKTS];
  int bid = blockIdx.x, tid = threadIdx.x;
  if (bid == NP1 && tid == 0) *done = 0;   // reset before coarse_scan (next kernel)
  if (bid < NP1) coarse_hist_body(bid, tid, ei, pcnt, c);
  else if (bid < NP1 + 128) prep_w_body(bid - NP1, tid, Wl1, Wr1, WtHi, WtLo);
  else prep_w2_body((bid - NP1 - 128) * 256 + tid, Wl2, Wr2, Wt2Hi, Wt2Lo);
}

// per-bucket scan; the LAST block to finish also runs the bucket scan
// (device-scope atomic + threadfence release/acquire)
__global__ __launch_bounds__(64) void coarse_scan(const int* __restrict__ pcnt,
                                                  int* __restrict__ goffArr,
                                                  int* __restrict__ tot,
                                                  int* __restrict__ bucketStart,
                                                  int* __restrict__ rowptr,
                                                  int* __restrict__ done) {
  int b = blockIdx.x;
  int lane = threadIdx.x;
  int carry = 0;
  for (int k0 = 0; k0 < NP1; k0 += 64) {
    int k = k0 + lane;
    int v = (k < NP1) ? pcnt[b * NP1 + k] : 0;
    int s = v;
    for (int off = 1; off < 64; off <<= 1) {
      int u = __shfl_up(s, off);
      if (lane >= off) s += u;
    }
    if (k < NP1) goffArr[b * NP1 + k] = carry + s - v;   // exclusive
    carry += __shfl(s, 63);
  }
  if (lane == 0) tot[b] = carry;
  __threadfence();                         // release tot[b]
  int old = 0;
  if (lane == 0) old = atomicAdd(done, 1);
  old = __shfl(old, 0);
  if (old == BKTS - 1) {                   // last block: all tot[] visible
    __threadfence();                       // acquire
    int carry2 = 0;
    for (int k0 = 0; k0 < BKTS; k0 += 64) {
      int k = k0 + lane;
      int v = (k < BKTS) ? tot[k] : 0;
      int s = v;
      for (int off = 1; off < 64; off <<= 1) {
        int u = __shfl_up(s, off);
        if (lane >= off) s += u;
      }
      if (k < BKTS) bucketStart[k] = carry2 + s - v;   // exclusive
      carry2 += __shfl(s, 63);
    }
    if (lane == 0) {
      bucketStart[BKTS] = carry2;          // == ETOT
      rowptr[NNODES] = ETOT;
    }
  }
}

// bin_phase1 (bids 0..NP1-1) || gemm1 blocks 0..GEMM1_H1-1
__global__ __launch_bounds__(256) void fusedB(const int* __restrict__ ei,
    const int* __restrict__ bucketStart, const int* __restrict__ goffArr,
    uint_t* __restrict__ binned,
    const float* __restrict__ x,
    const ushort_t* __restrict__ WtHi, const ushort_t* __restrict__ WtLo,
    const float* __restrict__ bl1, const float* __restrict__ br1,
    ushort_t* __restrict__ gl1, ushort_t* __restrict__ gr1) {
  __shared__ __align__(16) char smem[32 * 260 * 4];   // 33280 B union
  int bid = blockIdx.x, tid = threadIdx.x;
  if (bid < NP1) bin1_body(bid, tid, ei, bucketStart, goffArr, binned, smem);
  else gemm1_body((bid - NP1) * 32, tid, x, WtHi, WtLo, bl1, br1, gl1, gr1, smem);
}

// bin_phase2 (bids 0..BKTS-1) || gemm1 blocks GEMM1_H1..GEMM1_NB-1
__global__ __launch_bounds__(256) void fusedC(const uint_t* __restrict__ binned,
    const int* __restrict__ bucketStart, int* __restrict__ rowptr,
    int* __restrict__ csrc,
    const float* __restrict__ x,
    const ushort_t* __restrict__ WtHi, const ushort_t* __restrict__ WtLo,
    const float* __restrict__ bl1, const float* __restrict__ br1,
    ushort_t* __restrict__ gl1, ushort_t* __restrict__ gr1) {
  __shared__ __align__(16) char smem[32 * 260 * 4];
  int bid = blockIdx.x, tid = threadIdx.x;
  if (bid < BKTS) bin2_body(bid, tid, binned, bucketStart, rowptr, csrc, smem);
  else gemm1_body((GEMM1_H1 + bid - BKTS) * 32, tid, x, WtHi, WtLo, bl1, br1, gl1, gr1, smem);
}

// ---------------- GEMM2 via MFMA: 32 rows x 64 cols per block, grid 1563.
// A = h (already exact bf16 -> no lo term); W2 split-bf16 for fp32-quality. ----------------
__global__ __launch_bounds__(256) void gemm2_mfma(
    const ushort_t* __restrict__ hA,              // bf16 [N][128]
    const ushort_t* __restrict__ Wt2Hi, const ushort_t* __restrict__ Wt2Lo, // [64][128]
    const float* __restrict__ bl2, const float* __restrict__ br2,
    ushort_t* __restrict__ G1, ushort_t* __restrict__ G2) {
  constexpr int LDA = 132;
  __shared__ __align__(16) char smem[32 * 68 * 4];   // 8704 B; Cs overlays Ah (8448)
  ushort_t (*Ah)[LDA] = (ushort_t(*)[LDA])smem;
  float (*Cs)[68] = (float(*)[68])smem;
  int m0 = blockIdx.x * 32;
  int tid = threadIdx.x;
#pragma unroll
  for (int i = 0; i < 2; ++i) {                     // 512 items: 32 rows x 16 chunks(8)
    int it = i * 256 + tid;
    int row = it >> 4, c8 = (it & 15) * 8;
    int gm = m0 + row;
    uint4 v = (gm < NNODES) ? *(const uint4*)&hA[(size_t)gm * 128 + c8]
                            : make_uint4(0u, 0u, 0u, 0u);
    uint2 lo, hi;
    lo.x = v.x; lo.y = v.y; hi.x = v.z; hi.y = v.w;
    *(uint2*)&Ah[row][c8] = lo;                     // 8B stores: always aligned at LDA=132
    *(uint2*)&Ah[row][c8 + 4] = hi;
  }
  __syncthreads();
  int wave = tid >> 6, lane = tid & 63;
  int quad = lane >> 4, nl = lane & 15;
  int n = wave * 16 + nl;                           // output concat col 0..63
  f32x4 acc2[2];
  acc2[0] = (f32x4){0.f, 0.f, 0.f, 0.f};
  acc2[1] = (f32x4){0.f, 0.f, 0.f, 0.f};
#pragma unroll
  for (int kc = 0; kc < 4; ++kc) {
    int klane = kc * 32 + quad * 8;
    short8 a0 = *(const short8*)&Ah[nl][klane];
    short8 a1 = *(const short8*)&Ah[16 + nl][klane];
    short8 bh = *(const short8*)&Wt2Hi[(size_t)n * 128 + klane];
    short8 bl = *(const short8*)&Wt2Lo[(size_t)n * 128 + klane];
    acc2[0] = __builtin_amdgcn_mfma_f32_16x16x32_bf16(a0, bh, acc2[0], 0, 0, 0);
    acc2[0] = __builtin_amdgcn_mfma_f32_16x16x32_bf16(a0, bl, acc2[0], 0, 0, 0);
    acc2[1] = __builtin_amdgcn_mfma_f32_16x16x32_bf16(a1, bh, acc2[1], 0, 0, 0);
    acc2[1] = __builtin_amdgcn_mfma_f32_16x16x32_bf16(a1, bl, acc2[1], 0, 0, 0);
  }
  float bb = (n < 32) ? bl2[n] : br2[n - 32];
  __syncthreads();   // A reads done before Cs overlays the same LDS
#pragma unroll
  for (int tm = 0; tm < 2; ++tm)
#pragma unroll
    for (int r = 0; r < 4; ++r)
      Cs[16 * tm + 4 * quad + r][n] = acc2[tm][r] + bb;
  __syncthreads();
#pragma unroll
  for (int i = 0; i < 2; ++i) {                     // 512 items: 32 rows x 16 chunks(4col)
    int it = i * 256 + tid;
    int row = it >> 4, c4 = (it & 15) * 4;
    int gm = m0 + row;
    if (gm < NNODES) {
      uint2 pk;
      pk.x = (uint_t)f2bf(Cs[row][c4 + 0]) | ((uint_t)f2bf(Cs[row][c4 + 1]) << 16);
      pk.y = (uint_t)f2bf(Cs[row][c4 + 2]) | ((uint_t)f2bf(Cs[row][c4 + 3]) << 16);
      if (c4 < 32) *(uint2*)&G1[(size_t)gm * 32 + c4] = pk;
      else         *(uint2*)&G2[(size_t)gm * 32 + (c4 - 32)] = pk;
    }
  }
}

// ---------------- layer 1: wave/node (2 waves/block), 16 lanes/edge, 4 edges/iter,
// 2-deep register prefetch + packed-f32 (VOP3P) score/accumulate.
// Score: e' = sum_c (log2e*att_c) * lrelu(t_c), lrelu = max(t, 0.2t);
// dst-side linear term cancels in segment softmax. ----------------
__global__ __launch_bounds__(128) void gat1_edge(const int* __restrict__ rowptr,
                          const int* __restrict__ csrc,
                          const ushort_t* __restrict__ glb,    // bf16 [N][128]
                          const ushort_t* __restrict__ grb,    // bf16 [N][128]
                          const float* __restrict__ att, const float* __restrict__ bias,
                          ushort_t* __restrict__ hout) {       // bf16 [N][128]
  int node = blockIdx.x * 2 + (threadIdx.x >> 6);
  if (node >= NNODES) return;
  int lane = threadIdx.x & 63;
  int eslot = lane >> 4;        // 4 edge slots
  int q = lane & 15;            // 16 lanes per edge; lane covers 8 channels (4 pairs)
  int c8 = q * 8;               // head = q>>2
  const float L2E = 1.4426950408889634f;  // log2(e), folded into att
  f32x2 ap[4];
#pragma unroll
  for (int p = 0; p < 4; ++p) {
    ap[p].x = L2E * att[c8 + 2 * p];
    ap[p].y = L2E * att[c8 + 2 * p + 1];
  }
  uint4 ug = *(const uint4*)(grb + (size_t)node * 128 + c8);
  f32x2 grp[4];
  grp[0] = unpk2(ug.x); grp[1] = unpk2(ug.y);
  grp[2] = unpk2(ug.z); grp[3] = unpk2(ug.w);
  int start = rowptr[node], end = rowptr[node + 1];
  float denom = 0.f;
  f32x2 Ap[4];
#pragma unroll
  for (int p = 0; p < 4; ++p) Ap[p] = (f32x2){0.f, 0.f};
  const char* glc = (const char*)glb;
  uint_t coff = (uint_t)(c8 * 2);
  for (int b = start; b < end; b += 64) {
    int nb = end - b; if (nb > 64) nb = 64;
    int sidx = (lane < nb) ? csrc[b + lane] : 0;
    // 2-deep prefetch pipeline: up0 (group j), up1 (group j+4) in flight
    bool pv0 = eslot < nb;
    int s0 = __shfl(sidx, eslot);
    uint4 up0 = *(const uint4*)(glc + (((uint_t)s0 << 8) + coff));
    int j1 = 4 + eslot;
    bool pv1 = j1 < nb;
    int s1 = __shfl(sidx, pv1 ? j1 : 0);
    uint4 up1 = *(const uint4*)(glc + (((uint_t)s1 << 8) + coff));
    for (int j = 0; j < nb; j += 4) {
      // issue load for group j+8 (keeps 2 gathers outstanding)
      int jn = j + 8 + eslot;
      bool pvn = jn < nb;
      int sn = __shfl(sidx, pvn ? jn : 0);
      uint4 upn = *(const uint4*)(glc + (((uint_t)sn << 8) + coff));
      f32x2 gp[4];
      gp[0] = unpk2(up0.x); gp[1] = unpk2(up0.y);
      gp[2] = unpk2(up0.z); gp[3] = unpk2(up0.w);
      f32x2 t, vac;
      t = gp[0] + grp[0];
      vac = ap[0] * __builtin_elementwise_max(t, t * NEG);
      t = gp[1] + grp[1];
      vac = __builtin_elementwise_fma(ap[1], __builtin_elementwise_max(t, t * NEG), vac);
      t = gp[2] + grp[2];
      vac = __builtin_elementwise_fma(ap[2], __builtin_elementwise_max(t, t * NEG), vac);
      t = gp[3] + grp[3];
      vac = __builtin_elementwise_fma(ap[3], __builtin_elementwise_max(t, t * NEG), vac);
      float v = vac.x + vac.y;
      v += __shfl_xor(v, 1); v += __shfl_xor(v, 2);   // e[head] over 4 lanes (32 ch)
      float ex = pv0 ? exp2f(v) : 0.f;                // |e| bounded: max-free softmax
      denom += ex;
      f32x2 exv; exv.x = ex; exv.y = ex;
#pragma unroll
      for (int p = 0; p < 4; ++p)
        Ap[p] = __builtin_elementwise_fma(exv, gp[p], Ap[p]);
      up0 = up1; pv0 = pv1;
      up1 = upn; pv1 = pvn;
    }
  }
  denom += __shfl_xor(denom, 16); denom += __shfl_xor(denom, 32);
#pragma unroll
  for (int p = 0; p < 4; ++p) {
    Ap[p].x += __shfl_xor(Ap[p].x, 16); Ap[p].x += __shfl_xor(Ap[p].x, 32);
    Ap[p].y += __shfl_xor(Ap[p].y, 16); Ap[p].y += __shfl_xor(Ap[p].y, 32);
  }
  if (eslot < 2) {
    float inv = __builtin_amdgcn_rcpf(denom);
    // eslot 0 -> channels c8..c8+3 (Ap[0],Ap[1]); eslot 1 -> c8+4..c8+7 (Ap[2],Ap[3])
    f32x2 Ax0 = (eslot == 0) ? Ap[0] : Ap[2];
    f32x2 Ax1 = (eslot == 0) ? Ap[1] : Ap[3];
    int off = c8 + 4 * eslot;
    float4 bv = *(const float4*)(bias + off);
    float o0 = Ax0.x * inv + bv.x, o1 = Ax0.y * inv + bv.y;
    float o2 = Ax1.x * inv + bv.z, o3 = Ax1.y * inv + bv.w;
    o0 = o0 > 0.f ? o0 : __expf(o0) - 1.f;   // ELU
    o1 = o1 > 0.f ? o1 : __expf(o1) - 1.f;
    o2 = o2 > 0.f ? o2 : __expf(o2) - 1.f;
    o3 = o3 > 0.f ? o3 : __expf(o3) - 1.f;
    uint2 pk;
    pk.x = (uint_t)f2bf(o0) | ((uint_t)f2bf(o1) << 16);
    pk.y = (uint_t)f2bf(o2) | ((uint_t)f2bf(o3) << 16);
    *(uint2*)&hout[(size_t)node * 128 + off] = pk;
  }
}

// ---------------- layer 2: wave/node (2 waves/block), 8 lanes/edge (4 ch = 2 pairs),
// 8 edges/iter, 2-deep prefetch, packed-f32 score/accumulate ----------------
__global__ __launch_bounds__(128) void gat2_edge(const int* __restrict__ rowptr,
                          const int* __restrict__ csrc,
                          const ushort_t* __restrict__ gl, const ushort_t* __restrict__ gr,
                          const float* __restrict__ att, const float* __restrict__ bias,
                          float* __restrict__ out) {
  int node = blockIdx.x * 2 + (threadIdx.x >> 6);
  if (node >= NNODES) return;
  int lane = threadIdx.x & 63;
  int eslot = lane >> 3;        // 8 edge slots
  int q = lane & 7;             // 8 lanes per edge, 4 ch each (2 pairs)
  int c4 = q * 4;
  const float L2E = 1.4426950408889634f;
  f32x2 ap[2];
  ap[0].x = L2E * att[c4 + 0]; ap[0].y = L2E * att[c4 + 1];
  ap[1].x = L2E * att[c4 + 2]; ap[1].y = L2E * att[c4 + 3];
  uint2 ugr = *(const uint2*)(gr + (size_t)node * 32 + c4);
  f32x2 grp[2];
  grp[0] = unpk2(ugr.x); grp[1] = unpk2(ugr.y);
  int start = rowptr[node], end = rowptr[node + 1];
  float denom = 0.f;
  f32x2 Ap[2];
  Ap[0] = (f32x2){0.f, 0.f}; Ap[1] = (f32x2){0.f, 0.f};
  const char* glc = (const char*)gl;
  uint_t coff = (uint_t)(c4 * 2);
  for (int b = start; b < end; b += 64) {
    int nb = end - b; if (nb > 64) nb = 64;
    int sidx = (lane < nb) ? csrc[b + lane] : 0;
    bool pv0 = eslot < nb;
    int s0 = __shfl(sidx, eslot);
    uint2 u0 = *(const uint2*)(glc + (((uint_t)s0 << 6) + coff));
    int j1 = 8 + eslot;
    bool pv1 = j1 < nb;
    int s1 = __shfl(sidx, pv1 ? j1 : 0);
    uint2 u1 = *(const uint2*)(glc + (((uint_t)s1 << 6) + coff));
    for (int j = 0; j < nb; j += 8) {
      int jn = j + 16 + eslot;
      bool pvn = jn < nb;
      int sn = __shfl(sidx, pvn ? jn : 0);
      uint2 un = *(const uint2*)(glc + (((uint_t)sn << 6) + coff));
      f32x2 gp[2];
      gp[0] = unpk2(u0.x); gp[1] = unpk2(u0.y);
      f32x2 t, vac;
      t = gp[0] + grp[0];
      vac = ap[0] * __builtin_elementwise_max(t, t * NEG);
      t = gp[1] + grp[1];
      vac = __builtin_elementwise_fma(ap[1], __builtin_elementwise_max(t, t * NEG), vac);
      float v = vac.x + vac.y;
      v += __shfl_xor(v, 1); v += __shfl_xor(v, 2); v += __shfl_xor(v, 4);
      float ex = pv0 ? exp2f(v) : 0.f;
      denom += ex;
      f32x2 exv; exv.x = ex; exv.y = ex;
      Ap[0] = __builtin_elementwise_fma(exv, gp[0], Ap[0]);
      Ap[1] = __builtin_elementwise_fma(exv, gp[1], Ap[1]);
      u0 = u1; pv0 = pv1;
      u1 = un; pv1 = pvn;
    }
  }
  denom += __shfl_xor(denom, 8); denom += __shfl_xor(denom, 16); denom += __shfl_xor(denom, 32);
#pragma unroll
  for (int p = 0; p < 2; ++p) {
    Ap[p].x += __shfl_xor(Ap[p].x, 8); Ap[p].x += __shfl_xor(Ap[p].x, 16); Ap[p].x += __shfl_xor(Ap[p].x, 32);
    Ap[p].y += __shfl_xor(Ap[p].y, 8); Ap[p].y += __shfl_xor(Ap[p].y, 16); Ap[p].y += __shfl_xor(Ap[p].y, 32);
  }
  if (eslot == 0) {
    float inv = __builtin_amdgcn_rcpf(denom);
    float4 bv = *(const float4*)(bias + c4);
    float4 o;
    o.x = Ap[0].x * inv + bv.x; o.y = Ap[0].y * inv + bv.y;
    o.z = Ap[1].x * inv + bv.z; o.w = Ap[1].y * inv + bv.w;
    *(float4*)(out + (size_t)node * 32 + c4) = o;
  }
}

extern "C" void kernel_launch(void* const* d_in, const int* in_sizes, int n_in,
                              void* d_out, int out_size, void* d_ws, size_t ws_size,
                              hipStream_t stream) {
  const float* x     = (const float*)d_in[0];
  const int*   ei    = (const int*)  d_in[1];
  const float* Wl1   = (const float*)d_in[2];
  const float* bl1   = (const float*)d_in[3];
  const float* Wr1   = (const float*)d_in[4];
  const float* br1   = (const float*)d_in[5];
  const float* att1  = (const float*)d_in[6];
  const float* bias1 = (const float*)d_in[7];
  const float* Wl2   = (const float*)d_in[8];
  const float* bl2   = (const float*)d_in[9];
  const float* Wr2   = (const float*)d_in[10];
  const float* br2   = (const float*)d_in[11];
  const float* att2  = (const float*)d_in[12];
  const float* bias2 = (const float*)d_in[13];
  float* out = (float*)d_out;

  char* w = (char*)d_ws;
  auto carve = [&](size_t bytes) {
    char* p = w;
    w += (bytes + 255) & ~(size_t)255;
    return p;
  };
  ushort_t* gl1 = (ushort_t*)carve((size_t)NNODES * 128 * 2);   // bf16 gather table
  ushort_t* gr1 = (ushort_t*)carve((size_t)NNODES * 128 * 2);   // bf16
  ushort_t* h   = (ushort_t*)carve((size_t)NNODES * 128 * 2);   // bf16
  ushort_t* gl2 = (ushort_t*)carve((size_t)NNODES * 32 * 2);    // bf16 (fits XCD L2)
  ushort_t* gr2 = (ushort_t*)carve((size_t)NNODES * 32 * 2);    // bf16
  ushort_t* WtHi = (ushort_t*)carve((size_t)256 * 128 * 2);
  ushort_t* WtLo = (ushort_t*)carve((size_t)256 * 128 * 2);
  ushort_t* Wt2Hi = (ushort_t*)carve((size_t)64 * 128 * 2);
  ushort_t* Wt2Lo = (ushort_t*)carve((size_t)64 * 128 * 2);
  int* pcnt    = (int*)carve((size_t)NP1 * BKTS * 4);
  int* goffArr = (int*)carve((size_t)NP1 * BKTS * 4);
  int* tot     = (int*)carve((size_t)BKTS * 4);
  int* bucketStart = (int*)carve((size_t)(BKTS + 1) * 4);
  int* rowptr = (int*)carve((size_t)(NNODES + 1) * 4);
  uint_t* binned = (uint_t*)carve((size_t)ETOT * 4);
  int* csrc = (int*)carve((size_t)ETOT * 4);
  int* done = (int*)carve(4);

  // CSR pipeline and GEMM1 pipeline are independent until gat1; overlap them.
  fusedA<<<NP1 + 128 + 32, 256, 0, stream>>>(ei, pcnt, Wl1, Wr1, WtHi, WtLo,
                                             Wl2, Wr2, Wt2Hi, Wt2Lo, done);
  coarse_scan<<<BKTS, 64, 0, stream>>>(pcnt, goffArr, tot, bucketStart, rowptr, done);
  fusedB<<<NP1 + GEMM1_H1, 256, 0, stream>>>(ei, bucketStart, goffArr, binned,
                                             x, WtHi, WtLo, bl1, br1, gl1, gr1);
  fusedC<<<BKTS + GEMM1_H2, 256, 0, stream>>>(binned, bucketStart, rowptr, csrc,
                                              x, WtHi, WtLo, bl1, br1, gl1, gr1);
  gat1_edge<<<(NNODES + 1) / 2, 128, 0, stream>>>(rowptr, csrc, gl1, gr1, att1, bias1, h);
  gemm2_mfma<<<GEMM1_NB, 256, 0, stream>>>(h, Wt2Hi, Wt2Lo, bl2, br2, gl2, gr2);
  gat2_edge<<<(NNODES + 1) / 2, 128, 0, stream>>>(rowptr, csrc, gl2, gr2, att2, bias2, out);
}

// Round 11
// 226.975 us; speedup vs baseline: 1.0057x; 1.0057x over previous
//
#include <hip/hip_runtime.h>

#define NNODES 50000
#define NEDGES 800000
#define ETOT   (NNODES + NEDGES)   // 850000 (edges + self loops)
#define NEG 0.2f
#define BKTS 196                   // coarse buckets of 256 nodes (49999>>8 = 195)
#define P1E 4096                   // edges per phase-1 block
#define NP1 ((ETOT + P1E - 1) / P1E)   // 208
#define GEMM1_NB ((NNODES + 31) / 32)  // 1563
#define GEMM1_H1 782
#define GEMM1_H2 (GEMM1_NB - GEMM1_H1) // 781

typedef unsigned short ushort_t;
typedef unsigned int uint_t;
typedef __attribute__((ext_vector_type(8))) short short8;   // 8 bf16 (4 VGPRs)
typedef __attribute__((ext_vector_type(4))) float f32x4;    // 4 fp32 acc

__device__ __forceinline__ ushort_t f2bf(float f) {   // RTN bf16
  uint_t u = __float_as_uint(f);
  u += 0x7FFFu + ((u >> 16) & 1u);
  return (ushort_t)(u >> 16);
}
__device__ __forceinline__ float bf2f(ushort_t h) {
  return __uint_as_float((uint_t)h << 16);
}

// ================= device bodies (fused below) =================

__device__ __forceinline__ void coarse_hist_body(int bid, int tid,
    const int* __restrict__ ei, int* __restrict__ pcnt, int* c /*BKTS in LDS*/) {
  for (int i = tid; i < BKTS; i += 256) c[i] = 0;
  __syncthreads();
  int e0 = bid * P1E;
#pragma unroll
  for (int t = 0; t < P1E / 256; ++t) {
    int i = e0 + t * 256 + tid;
    if (i < ETOT) {
      int dst = (i < NEDGES) ? ei[NEDGES + i] : (i - NEDGES);
      atomicAdd(&c[dst >> 8], 1);
    }
  }
  __syncthreads();
  for (int i = tid; i < BKTS; i += 256)
    pcnt[i * NP1 + bid] = c[i];
}

__device__ __forceinline__ void prep_w_body(int k, int n,
    const float* __restrict__ Wl1, const float* __restrict__ Wr1,
    ushort_t* __restrict__ WtHi, ushort_t* __restrict__ WtLo) {
  float w = (n < 128) ? Wl1[k * 128 + n] : Wr1[k * 128 + (n - 128)];
  ushort_t h = f2bf(w);
  WtHi[n * 128 + k] = h;
  WtLo[n * 128 + k] = f2bf(w - bf2f(h));
}

// W2 transpose + split-bf16: [64 concat cols][128 k]
__device__ __forceinline__ void prep_w2_body(int e,
    const float* __restrict__ Wl2, const float* __restrict__ Wr2,
    ushort_t* __restrict__ Wt2Hi, ushort_t* __restrict__ Wt2Lo) {
  int k = e & 127, n = e >> 7;     // e < 8192
  float w = (n < 32) ? Wl2[k * 32 + n] : Wr2[k * 32 + (n - 32)];
  ushort_t hh = f2bf(w);
  Wt2Hi[n * 128 + k] = hh;
  Wt2Lo[n * 128 + k] = f2bf(w - bf2f(hh));
}

__device__ __forceinline__ void bin1_body(int bid, int tid,
    const int* __restrict__ ei, const int* __restrict__ bucketStart,
    const int* __restrict__ goffArr, uint_t* __restrict__ binned, char* smemc) {
  int* cnt   = (int*)smemc;        // BKTS
  int* pref  = cnt + BKTS;
  int* fillL = pref + BKTS;
  uint_t* stage = (uint_t*)(fillL + BKTS);   // P1E
  int e0 = bid * P1E;
  for (int i = tid; i < BKTS; i += 256) { cnt[i] = 0; fillL[i] = 0; }
  __syncthreads();
  uint_t mypk[P1E / 256];
#pragma unroll
  for (int t = 0; t < P1E / 256; ++t) {
    int i = e0 + t * 256 + tid;
    if (i < ETOT) {
      int dst = (i < NEDGES) ? ei[NEDGES + i] : (i - NEDGES);
      int src = (i < NEDGES) ? ei[i] : dst;
      int b = dst >> 8;
      mypk[t] = (uint_t)src | ((uint_t)(dst & 255) << 16) | ((uint_t)b << 24);
      atomicAdd(&cnt[b], 1);
    } else mypk[t] = 0xFFFFFFFFu;   // b=255 >= BKTS -> skipped
  }
  __syncthreads();
  if (tid < 64) {                  // wave-0 exclusive scan of cnt -> pref
    int carry = 0;
    for (int k0 = 0; k0 < BKTS; k0 += 64) {
      int k = k0 + tid;
      int v = (k < BKTS) ? cnt[k] : 0;
      int s = v;
      for (int off = 1; off < 64; off <<= 1) {
        int u = __shfl_up(s, off);
        if (tid >= off) s += u;
      }
      if (k < BKTS) pref[k] = carry + s - v;
      carry += __shfl(s, 63);
    }
  }
  __syncthreads();
#pragma unroll
  for (int t = 0; t < P1E / 256; ++t) {
    uint_t pk = mypk[t];
    int b = pk >> 24;
    if (b < BKTS) {
      int p = pref[b] + atomicAdd(&fillL[b], 1);
      stage[p] = pk;
    }
  }
  __syncthreads();
  int total = (e0 + P1E <= ETOT) ? P1E : (ETOT - e0);
  for (int j = tid; j < total; j += 256) {
    uint_t pk = stage[j];
    int b = pk >> 24;
    binned[bucketStart[b] + goffArr[b * NP1 + bid] + (j - pref[b])] = pk;
  }
}

__device__ __forceinline__ void bin2_body(int b, int tid,
    const uint_t* __restrict__ binned, const int* __restrict__ bucketStart,
    int* __restrict__ rowptr, int* __restrict__ csrc, char* smemc) {
  int* cnt   = (int*)smemc;        // 256
  int* pref  = cnt + 256;
  int* fillL = pref + 256;
  int* outS  = fillL + 256;        // up to 7424 ints within 33280-B union
  int base = bucketStart[b];
  int cntAll = bucketStart[b + 1] - base;
  cnt[tid] = 0; fillL[tid] = 0;
  __syncthreads();
  for (int j = tid; j < cntAll; j += 256)
    atomicAdd(&cnt[(binned[base + j] >> 16) & 255], 1);
  __syncthreads();
  if (tid < 64) {                  // wave-0 exclusive scan of 256 counts
    int carry = 0;
    for (int k0 = 0; k0 < 256; k0 += 64) {
      int k = k0 + tid;
      int v = cnt[k];
      int s = v;
      for (int off = 1; off < 64; off <<= 1) {
        int u = __shfl_up(s, off);
        if (tid >= off) s += u;
      }
      pref[k] = carry + s - v;
      carry += __shfl(s, 63);
    }
  }
  __syncthreads();
  int node = b * 256 + tid;
  if (node < NNODES) rowptr[node] = base + pref[tid];
  for (int j = tid; j < cntAll; j += 256) {
    uint_t pk = binned[base + j];
    int d = (pk >> 16) & 255;
    int p = pref[d] + atomicAdd(&fillL[d], 1);
    outS[p] = (int)(pk & 0xFFFF);
  }
  __syncthreads();
  for (int j = tid; j < cntAll; j += 256)
    csrc[base + j] = outS[j];
}

// GEMM1 body via MFMA (split-bf16 = fp32-quality); round-0/5 proven structure
// (single-pass Cs[32][260] epilogue).
__device__ __forceinline__ void gemm1_body(int m0, int tid,
    const float* __restrict__ x,
    const ushort_t* __restrict__ WtHi, const ushort_t* __restrict__ WtLo,
    const float* __restrict__ bl1, const float* __restrict__ br1,
    ushort_t* __restrict__ gl1, ushort_t* __restrict__ gr1, char* smem) {
  constexpr int LDA = 132;
  ushort_t (*Ahi)[LDA] = (ushort_t(*)[LDA])smem;
  ushort_t (*Alo)[LDA] = (ushort_t(*)[LDA])(smem + 32 * LDA * 2);
  float (*Cs)[260] = (float(*)[260])smem;   // overlays Ahi/Alo after compute
#pragma unroll
  for (int i = 0; i < 4; ++i) {
    int it = i * 256 + tid;
    int row = it >> 5, c4 = it & 31;
    int gm = m0 + row;
    float4 v = (gm < NNODES) ? *(const float4*)&x[(size_t)gm * 128 + 4 * c4]
                             : make_float4(0.f, 0.f, 0.f, 0.f);
    ushort_t h0 = f2bf(v.x), h1 = f2bf(v.y), h2 = f2bf(v.z), h3 = f2bf(v.w);
    ushort_t l0 = f2bf(v.x - bf2f(h0)), l1 = f2bf(v.y - bf2f(h1));
    ushort_t l2 = f2bf(v.z - bf2f(h2)), l3 = f2bf(v.w - bf2f(h3));
    uint2 ph, pl;
    ph.x = (uint_t)h0 | ((uint_t)h1 << 16); ph.y = (uint_t)h2 | ((uint_t)h3 << 16);
    pl.x = (uint_t)l0 | ((uint_t)l1 << 16); pl.y = (uint_t)l2 | ((uint_t)l3 << 16);
    *(uint2*)&Ahi[row][4 * c4] = ph;
    *(uint2*)&Alo[row][4 * c4] = pl;
  }
  __syncthreads();
  int wave = tid >> 6, lane = tid & 63;
  int quad = lane >> 4, nl = lane & 15;
  int nb = wave * 64;
  f32x4 acc[2][4];
#pragma unroll
  for (int tm = 0; tm < 2; ++tm)
#pragma unroll
    for (int tn = 0; tn < 4; ++tn) acc[tm][tn] = (f32x4){0.f, 0.f, 0.f, 0.f};

#pragma unroll
  for (int kc = 0; kc < 4; ++kc) {
    int klane = kc * 32 + quad * 8;
    short8 ah[2], al[2], bh[4], bl[4];
#pragma unroll
    for (int tm = 0; tm < 2; ++tm) {
      ah[tm] = *(const short8*)&Ahi[16 * tm + nl][klane];
      al[tm] = *(const short8*)&Alo[16 * tm + nl][klane];
    }
#pragma unroll
    for (int tn = 0; tn < 4; ++tn) {
      size_t wo = (size_t)(nb + 16 * tn + nl) * 128 + klane;
      bh[tn] = *(const short8*)&WtHi[wo];
      bl[tn] = *(const short8*)&WtLo[wo];
    }
#pragma unroll
    for (int tm = 0; tm < 2; ++tm)
#pragma unroll
      for (int tn = 0; tn < 4; ++tn) {
        acc[tm][tn] = __builtin_amdgcn_mfma_f32_16x16x32_bf16(ah[tm], bh[tn], acc[tm][tn], 0, 0, 0);
        acc[tm][tn] = __builtin_amdgcn_mfma_f32_16x16x32_bf16(ah[tm], bl[tn], acc[tm][tn], 0, 0, 0);
        acc[tm][tn] = __builtin_amdgcn_mfma_f32_16x16x32_bf16(al[tm], bh[tn], acc[tm][tn], 0, 0, 0);
      }
  }
  float bb[4];
#pragma unroll
  for (int tn = 0; tn < 4; ++tn) {
    int n = nb + 16 * tn + nl;
    bb[tn] = (n < 128) ? bl1[n] : br1[n - 128];
  }
  __syncthreads();   // all A-tile reads done before Cs overlays the same LDS
#pragma unroll
  for (int tm = 0; tm < 2; ++tm)
#pragma unroll
    for (int tn = 0; tn < 4; ++tn)
#pragma unroll
      for (int r = 0; r < 4; ++r)
        Cs[16 * tm + 4 * quad + r][nb + 16 * tn + nl] = acc[tm][tn][r] + bb[tn];
  __syncthreads();
#pragma unroll
  for (int i = 0; i < 2; ++i) {     // gl1 (cols 0..127, bf16)
    int it = i * 256 + tid;
    int row = it >> 4, oc = (it & 15) * 8;
    int gm = m0 + row;
    if (gm < NNODES) {
      uint4 pk;
      pk.x = (uint_t)f2bf(Cs[row][oc + 0]) | ((uint_t)f2bf(Cs[row][oc + 1]) << 16);
      pk.y = (uint_t)f2bf(Cs[row][oc + 2]) | ((uint_t)f2bf(Cs[row][oc + 3]) << 16);
      pk.z = (uint_t)f2bf(Cs[row][oc + 4]) | ((uint_t)f2bf(Cs[row][oc + 5]) << 16);
      pk.w = (uint_t)f2bf(Cs[row][oc + 6]) | ((uint_t)f2bf(Cs[row][oc + 7]) << 16);
      *(uint4*)&gl1[(size_t)gm * 128 + oc] = pk;
    }
  }
#pragma unroll
  for (int i = 0; i < 2; ++i) {     // gr1 (cols 128..255, bf16)
    int it = i * 256 + tid;
    int row = it >> 4, oc = (it & 15) * 8;
    int gm = m0 + row;
    if (gm < NNODES) {
      uint4 pk;
      pk.x = (uint_t)f2bf(Cs[row][128 + oc + 0]) | ((uint_t)f2bf(Cs[row][128 + oc + 1]) << 16);
      pk.y = (uint_t)f2bf(Cs[row][128 + oc + 2]) | ((uint_t)f2bf(Cs[row][128 + oc + 3]) << 16);
      pk.z = (uint_t)f2bf(Cs[row][128 + oc + 4]) | ((uint_t)f2bf(Cs[row][128 + oc + 5]) << 16);
      pk.w = (uint_t)f2bf(Cs[row][128 + oc + 6]) | ((uint_t)f2bf(Cs[row][128 + oc + 7]) << 16);
      *(uint4*)&gr1[(size_t)gm * 128 + oc] = pk;
    }
  }
}

// ================= fused kernels =================

// coarse_hist (0..NP1-1) || prep_w (NP1..NP1+127) || prep_w2 (NP1+128..NP1+159)
__global__ __launch_bounds__(256) void fusedA(const int* __restrict__ ei,
    int* __restrict__ pcnt,
    const float* __restrict__ Wl1, const float* __restrict__ Wr1,
    ushort_t* __restrict__ WtHi, ushort_t* __restrict__ WtLo,
    const float* __restrict__ Wl2, const float* __restrict__ Wr2,
    ushort_t* __restrict__ Wt2Hi, ushort_t* __restrict__ Wt2Lo,
    int* __restrict__ done) {
  __shared__ int c[BKTS];
  int bid = blockIdx.x, tid = threadIdx.x;
  if (bid == NP1 && tid == 0) *done = 0;   // reset before coarse_scan (next kernel)
  if (bid < NP1) coarse_hist_body(bid, tid, ei, pcnt, c);
  else if (bid < NP1 + 128) prep_w_body(bid - NP1, tid, Wl1, Wr1, WtHi, WtLo);
  else prep_w2_body((bid - NP1 - 128) * 256 + tid, Wl2, Wr2, Wt2Hi, Wt2Lo);
}

// per-bucket scan; the LAST block to finish also runs the bucket scan
// (device-scope atomic + threadfence release/acquire)
__global__ __launch_bounds__(64) void coarse_scan(const int* __restrict__ pcnt,
                                                  int* __restrict__ goffArr,
                                                  int* __restrict__ tot,
                                                  int* __restrict__ bucketStart,
                                                  int* __restrict__ rowptr,
                                                  int* __restrict__ done) {
  int b = blockIdx.x;
  int lane = threadIdx.x;
  int carry = 0;
  for (int k0 = 0; k0 < NP1; k0 += 64) {
    int k = k0 + lane;
    int v = (k < NP1) ? pcnt[b * NP1 + k] : 0;
    int s = v;
    for (int off = 1; off < 64; off <<= 1) {
      int u = __shfl_up(s, off);
      if (lane >= off) s += u;
    }
    if (k < NP1) goffArr[b * NP1 + k] = carry + s - v;   // exclusive
    carry += __shfl(s, 63);
  }
  if (lane == 0) tot[b] = carry;
  __threadfence();                         // release tot[b]
  int old = 0;
  if (lane == 0) old = atomicAdd(done, 1);
  old = __shfl(old, 0);
  if (old == BKTS - 1) {                   // last block: all tot[] visible
    __threadfence();                       // acquire
    int carry2 = 0;
    for (int k0 = 0; k0 < BKTS; k0 += 64) {
      int k = k0 + lane;
      int v = (k < BKTS) ? tot[k] : 0;
      int s = v;
      for (int off = 1; off < 64; off <<= 1) {
        int u = __shfl_up(s, off);
        if (lane >= off) s += u;
      }
      if (k < BKTS) bucketStart[k] = carry2 + s - v;   // exclusive
      carry2 += __shfl(s, 63);
    }
    if (lane == 0) {
      bucketStart[BKTS] = carry2;          // == ETOT
      rowptr[NNODES] = ETOT;
    }
  }
}

// bin_phase1 (bids 0..NP1-1) || gemm1 blocks 0..GEMM1_H1-1
__global__ __launch_bounds__(256) void fusedB(const int* __restrict__ ei,
    const int* __restrict__ bucketStart, const int* __restrict__ goffArr,
    uint_t* __restrict__ binned,
    const float* __restrict__ x,
    const ushort_t* __restrict__ WtHi, const ushort_t* __restrict__ WtLo,
    const float* __restrict__ bl1, const float* __restrict__ br1,
    ushort_t* __restrict__ gl1, ushort_t* __restrict__ gr1) {
  __shared__ __align__(16) char smem[32 * 260 * 4];   // 33280 B union
  int bid = blockIdx.x, tid = threadIdx.x;
  if (bid < NP1) bin1_body(bid, tid, ei, bucketStart, goffArr, binned, smem);
  else gemm1_body((bid - NP1) * 32, tid, x, WtHi, WtLo, bl1, br1, gl1, gr1, smem);
}

// bin_phase2 (bids 0..BKTS-1) || gemm1 blocks GEMM1_H1..GEMM1_NB-1
__global__ __launch_bounds__(256) void fusedC(const uint_t* __restrict__ binned,
    const int* __restrict__ bucketStart, int* __restrict__ rowptr,
    int* __restrict__ csrc,
    const float* __restrict__ x,
    const ushort_t* __restrict__ WtHi, const ushort_t* __restrict__ WtLo,
    const float* __restrict__ bl1, const float* __restrict__ br1,
    ushort_t* __restrict__ gl1, ushort_t* __restrict__ gr1) {
  __shared__ __align__(16) char smem[32 * 260 * 4];
  int bid = blockIdx.x, tid = threadIdx.x;
  if (bid < BKTS) bin2_body(bid, tid, binned, bucketStart, rowptr, csrc, smem);
  else gemm1_body((GEMM1_H1 + bid - BKTS) * 32, tid, x, WtHi, WtLo, bl1, br1, gl1, gr1, smem);
}

// ---------------- GEMM2 via MFMA: 32 rows x 64 cols per block, grid 1563.
// A = h (already exact bf16 -> no lo term); W2 split-bf16 for fp32-quality.
// Staging mirrors gemm1 exactly (uint2 stores, short8 reads, LDA=132). ----------------
__global__ __launch_bounds__(256) void gemm2_mfma(
    const ushort_t* __restrict__ hA,              // bf16 [N][128]
    const ushort_t* __restrict__ Wt2Hi, const ushort_t* __restrict__ Wt2Lo, // [64][128]
    const float* __restrict__ bl2, const float* __restrict__ br2,
    ushort_t* __restrict__ G1, ushort_t* __restrict__ G2) {
  constexpr int LDA = 132;
  __shared__ __align__(16) char smem[32 * 68 * 4];   // 8704 B; Cs overlays Ah (8448)
  ushort_t (*Ah)[LDA] = (ushort_t(*)[LDA])smem;
  float (*Cs)[68] = (float(*)[68])smem;
  int m0 = blockIdx.x * 32;
  int tid = threadIdx.x;
#pragma unroll
  for (int i = 0; i < 2; ++i) {                     // 512 items: 32 rows x 16 chunks(8)
    int it = i * 256 + tid;
    int row = it >> 4, c8 = (it & 15) * 8;
    int gm = m0 + row;
    uint4 v = (gm < NNODES) ? *(const uint4*)&hA[(size_t)gm * 128 + c8]
                            : make_uint4(0u, 0u, 0u, 0u);
    uint2 lo, hi;
    lo.x = v.x; lo.y = v.y; hi.x = v.z; hi.y = v.w;
    *(uint2*)&Ah[row][c8] = lo;                     // 8B stores: always aligned at LDA=132
    *(uint2*)&Ah[row][c8 + 4] = hi;
  }
  __syncthreads();
  int wave = tid >> 6, lane = tid & 63;
  int quad = lane >> 4, nl = lane & 15;
  int n = wave * 16 + nl;                           // output concat col 0..63
  f32x4 acc2[2];
  acc2[0] = (f32x4){0.f, 0.f, 0.f, 0.f};
  acc2[1] = (f32x4){0.f, 0.f, 0.f, 0.f};
#pragma unroll
  for (int kc = 0; kc < 4; ++kc) {
    int klane = kc * 32 + quad * 8;
    short8 a0 = *(const short8*)&Ah[nl][klane];
    short8 a1 = *(const short8*)&Ah[16 + nl][klane];
    short8 bh = *(const short8*)&Wt2Hi[(size_t)n * 128 + klane];
    short8 bl = *(const short8*)&Wt2Lo[(size_t)n * 128 + klane];
    acc2[0] = __builtin_amdgcn_mfma_f32_16x16x32_bf16(a0, bh, acc2[0], 0, 0, 0);
    acc2[0] = __builtin_amdgcn_mfma_f32_16x16x32_bf16(a0, bl, acc2[0], 0, 0, 0);
    acc2[1] = __builtin_amdgcn_mfma_f32_16x16x32_bf16(a1, bh, acc2[1], 0, 0, 0);
    acc2[1] = __builtin_amdgcn_mfma_f32_16x16x32_bf16(a1, bl, acc2[1], 0, 0, 0);
  }
  float bb = (n < 32) ? bl2[n] : br2[n - 32];
  __syncthreads();   // A reads done before Cs overlays the same LDS
#pragma unroll
  for (int tm = 0; tm < 2; ++tm)
#pragma unroll
    for (int r = 0; r < 4; ++r)
      Cs[16 * tm + 4 * quad + r][n] = acc2[tm][r] + bb;
  __syncthreads();
#pragma unroll
  for (int i = 0; i < 2; ++i) {                     // 512 items: 32 rows x 16 chunks(4col)
    int it = i * 256 + tid;
    int row = it >> 4, c4 = (it & 15) * 4;
    int gm = m0 + row;
    if (gm < NNODES) {
      uint2 pk;
      pk.x = (uint_t)f2bf(Cs[row][c4 + 0]) | ((uint_t)f2bf(Cs[row][c4 + 1]) << 16);
      pk.y = (uint_t)f2bf(Cs[row][c4 + 2]) | ((uint_t)f2bf(Cs[row][c4 + 3]) << 16);
      if (c4 < 32) *(uint2*)&G1[(size_t)gm * 32 + c4] = pk;
      else         *(uint2*)&G2[(size_t)gm * 32 + (c4 - 32)] = pk;
    }
  }
}

// ---------------- layer 1: wave/node (2 waves/block), 16 lanes/edge, 4 edges/iter,
// 2-deep register prefetch pipeline + unified (branchless-select) store epilogue.
// Inline score: e' = log2e * sum_c att_c*(0.6 t + 0.4|t|); dst linear term cancels. ----------------
__global__ __launch_bounds__(128) void gat1_edge(const int* __restrict__ rowptr,
                          const int* __restrict__ csrc,
                          const ushort_t* __restrict__ glb,    // bf16 [N][128]
                          const ushort_t* __restrict__ grb,    // bf16 [N][128]
                          const float* __restrict__ att, const float* __restrict__ bias,
                          ushort_t* __restrict__ hout) {       // bf16 [N][128]
  int node = blockIdx.x * 2 + (threadIdx.x >> 6);
  if (node >= NNODES) return;
  int lane = threadIdx.x & 63;
  int eslot = lane >> 4;        // 4 edge slots
  int q = lane & 15;            // 16 lanes per edge; lane covers 8 channels
  int c8 = q * 8;               // head = q>>2
  const float C6 = 0.8656170245333781f;   // 0.6 * log2(e)
  const float C4 = 0.5770780163555854f;   // 0.4 * log2(e)
  float4 av0 = *(const float4*)(att + c8);
  float4 av1 = *(const float4*)(att + c8 + 4);
  float4 a60, a61, a40, a41;
  a60.x = C6 * av0.x; a60.y = C6 * av0.y; a60.z = C6 * av0.z; a60.w = C6 * av0.w;
  a61.x = C6 * av1.x; a61.y = C6 * av1.y; a61.z = C6 * av1.z; a61.w = C6 * av1.w;
  a40.x = C4 * av0.x; a40.y = C4 * av0.y; a40.z = C4 * av0.z; a40.w = C4 * av0.w;
  a41.x = C4 * av1.x; a41.y = C4 * av1.y; a41.z = C4 * av1.z; a41.w = C4 * av1.w;
  uint4 ug = *(const uint4*)(grb + (size_t)node * 128 + c8);
  float4 gr0, gr1v;
  gr0.x = __uint_as_float(ug.x << 16);  gr0.y = __uint_as_float(ug.x & 0xffff0000u);
  gr0.z = __uint_as_float(ug.y << 16);  gr0.w = __uint_as_float(ug.y & 0xffff0000u);
  gr1v.x = __uint_as_float(ug.z << 16); gr1v.y = __uint_as_float(ug.z & 0xffff0000u);
  gr1v.z = __uint_as_float(ug.w << 16); gr1v.w = __uint_as_float(ug.w & 0xffff0000u);
  int start = rowptr[node], end = rowptr[node + 1];
  float denom = 0.f;
  float4 A0 = make_float4(0.f, 0.f, 0.f, 0.f);
  float4 A1 = make_float4(0.f, 0.f, 0.f, 0.f);
  const char* glc = (const char*)glb;
  uint_t coff = (uint_t)(c8 * 2);
  for (int b = start; b < end; b += 64) {
    int nb = end - b; if (nb > 64) nb = 64;
    int sidx = (lane < nb) ? csrc[b + lane] : 0;
    // 2-deep prefetch pipeline: up0 (group j), up1 (group j+4) in flight
    bool pv0 = eslot < nb;
    int s0 = __shfl(sidx, eslot);
    uint4 up0 = *(const uint4*)(glc + (((uint_t)s0 << 8) + coff));
    int j1 = 4 + eslot;
    bool pv1 = j1 < nb;
    int s1 = __shfl(sidx, pv1 ? j1 : 0);
    uint4 up1 = *(const uint4*)(glc + (((uint_t)s1 << 8) + coff));
    for (int j = 0; j < nb; j += 4) {
      // issue load for group j+8 (keeps 2 gathers outstanding)
      int jn = j + 8 + eslot;
      bool pvn = jn < nb;
      int sn = __shfl(sidx, pvn ? jn : 0);
      uint4 upn = *(const uint4*)(glc + (((uint_t)sn << 8) + coff));
      float4 g0, g1;
      g0.x = __uint_as_float(up0.x << 16);
      g0.y = __uint_as_float(up0.x & 0xffff0000u);
      g0.z = __uint_as_float(up0.y << 16);
      g0.w = __uint_as_float(up0.y & 0xffff0000u);
      g1.x = __uint_as_float(up0.z << 16);
      g1.y = __uint_as_float(up0.z & 0xffff0000u);
      g1.z = __uint_as_float(up0.w << 16);
      g1.w = __uint_as_float(up0.w & 0xffff0000u);
      float t, v;
      t = g0.x + gr0.x;  v = fmaf(a40.x, fabsf(t), a60.x * t);
      t = g0.y + gr0.y;  v = fmaf(a60.y, t, v); v = fmaf(a40.y, fabsf(t), v);
      t = g0.z + gr0.z;  v = fmaf(a60.z, t, v); v = fmaf(a40.z, fabsf(t), v);
      t = g0.w + gr0.w;  v = fmaf(a60.w, t, v); v = fmaf(a40.w, fabsf(t), v);
      t = g1.x + gr1v.x; v = fmaf(a61.x, t, v); v = fmaf(a41.x, fabsf(t), v);
      t = g1.y + gr1v.y; v = fmaf(a61.y, t, v); v = fmaf(a41.y, fabsf(t), v);
      t = g1.z + gr1v.z; v = fmaf(a61.z, t, v); v = fmaf(a41.z, fabsf(t), v);
      t = g1.w + gr1v.w; v = fmaf(a61.w, t, v); v = fmaf(a41.w, fabsf(t), v);
      v += __shfl_xor(v, 1); v += __shfl_xor(v, 2);   // e[head] over 4 lanes (32 ch)
      float ex = pv0 ? exp2f(v) : 0.f;                // |e| bounded: max-free softmax
      denom += ex;
      A0.x = fmaf(ex, g0.x, A0.x); A0.y = fmaf(ex, g0.y, A0.y);
      A0.z = fmaf(ex, g0.z, A0.z); A0.w = fmaf(ex, g0.w, A0.w);
      A1.x = fmaf(ex, g1.x, A1.x); A1.y = fmaf(ex, g1.y, A1.y);
      A1.z = fmaf(ex, g1.z, A1.z); A1.w = fmaf(ex, g1.w, A1.w);
      up0 = up1; pv0 = pv1;
      up1 = upn; pv1 = pvn;
    }
  }
  denom += __shfl_xor(denom, 16); denom += __shfl_xor(denom, 32);
  A0.x += __shfl_xor(A0.x, 16); A0.x += __shfl_xor(A0.x, 32);
  A0.y += __shfl_xor(A0.y, 16); A0.y += __shfl_xor(A0.y, 32);
  A0.z += __shfl_xor(A0.z, 16); A0.z += __shfl_xor(A0.z, 32);
  A0.w += __shfl_xor(A0.w, 16); A0.w += __shfl_xor(A0.w, 32);
  A1.x += __shfl_xor(A1.x, 16); A1.x += __shfl_xor(A1.x, 32);
  A1.y += __shfl_xor(A1.y, 16); A1.y += __shfl_xor(A1.y, 32);
  A1.z += __shfl_xor(A1.z, 16); A1.z += __shfl_xor(A1.z, 32);
  A1.w += __shfl_xor(A1.w, 16); A1.w += __shfl_xor(A1.w, 32);
  if (eslot < 2) {
    float inv = __builtin_amdgcn_rcpf(denom);
    float4 Ax;
    Ax.x = (eslot == 0) ? A0.x : A1.x;
    Ax.y = (eslot == 0) ? A0.y : A1.y;
    Ax.z = (eslot == 0) ? A0.z : A1.z;
    Ax.w = (eslot == 0) ? A0.w : A1.w;
    int off = c8 + 4 * eslot;
    float4 bv = *(const float4*)(bias + off);
    float o0 = Ax.x * inv + bv.x, o1 = Ax.y * inv + bv.y;
    float o2 = Ax.z * inv + bv.z, o3 = Ax.w * inv + bv.w;
    o0 = o0 > 0.f ? o0 : __expf(o0) - 1.f;   // ELU
    o1 = o1 > 0.f ? o1 : __expf(o1) - 1.f;
    o2 = o2 > 0.f ? o2 : __expf(o2) - 1.f;
    o3 = o3 > 0.f ? o3 : __expf(o3) - 1.f;
    uint2 pk;
    pk.x = (uint_t)f2bf(o0) | ((uint_t)f2bf(o1) << 16);
    pk.y = (uint_t)f2bf(o2) | ((uint_t)f2bf(o3) << 16);
    *(uint2*)&hout[(size_t)node * 128 + off] = pk;
  }
}

// ---------------- layer 2: wave/node (2 waves/block), 8 lanes/edge (4 ch), 8 edges/iter,
// 2-deep prefetch, inline score (dst part cancels in softmax) ----------------
__global__ __launch_bounds__(128) void gat2_edge(const int* __restrict__ rowptr,
                          const int* __restrict__ csrc,
                          const ushort_t* __restrict__ gl, const ushort_t* __restrict__ gr,
                          const float* __restrict__ att, const float* __restrict__ bias,
                          float* __restrict__ out) {
  int node = blockIdx.x * 2 + (threadIdx.x >> 6);
  if (node >= NNODES) return;
  int lane = threadIdx.x & 63;
  int eslot = lane >> 3;        // 8 edge slots
  int q = lane & 7;             // 8 lanes per edge, 4 ch each
  int c4 = q * 4;
  const float C6 = 0.8656170245333781f;   // 0.6 * log2(e)
  const float C4f = 0.5770780163555854f;  // 0.4 * log2(e)
  float4 avc = *(const float4*)(att + c4);
  float4 a6, a4;
  a6.x = C6 * avc.x; a6.y = C6 * avc.y; a6.z = C6 * avc.z; a6.w = C6 * avc.w;
  a4.x = C4f * avc.x; a4.y = C4f * avc.y; a4.z = C4f * avc.z; a4.w = C4f * avc.w;
  uint2 ugr = *(const uint2*)(gr + (size_t)node * 32 + c4);
  float4 grd;
  grd.x = __uint_as_float(ugr.x << 16); grd.y = __uint_as_float(ugr.x & 0xffff0000u);
  grd.z = __uint_as_float(ugr.y << 16); grd.w = __uint_as_float(ugr.y & 0xffff0000u);
  int start = rowptr[node], end = rowptr[node + 1];
  float denom = 0.f;
  float4 A = make_float4(0.f, 0.f, 0.f, 0.f);
  const char* glc = (const char*)gl;
  uint_t coff = (uint_t)(c4 * 2);
  for (int b = start; b < end; b += 64) {
    int nb = end - b; if (nb > 64) nb = 64;
    int sidx = (lane < nb) ? csrc[b + lane] : 0;
    bool pv0 = eslot < nb;
    int s0 = __shfl(sidx, eslot);
    uint2 u0 = *(const uint2*)(glc + (((uint_t)s0 << 6) + coff));
    int j1 = 8 + eslot;
    bool pv1 = j1 < nb;
    int s1 = __shfl(sidx, pv1 ? j1 : 0);
    uint2 u1 = *(const uint2*)(glc + (((uint_t)s1 << 6) + coff));
    for (int j = 0; j < nb; j += 8) {
      int jn = j + 16 + eslot;
      bool pvn = jn < nb;
      int sn = __shfl(sidx, pvn ? jn : 0);
      uint2 un = *(const uint2*)(glc + (((uint_t)sn << 6) + coff));
      float4 g;
      g.x = __uint_as_float(u0.x << 16); g.y = __uint_as_float(u0.x & 0xffff0000u);
      g.z = __uint_as_float(u0.y << 16); g.w = __uint_as_float(u0.y & 0xffff0000u);
      float t, v;
      t = g.x + grd.x; v = fmaf(a4.x, fabsf(t), a6.x * t);
      t = g.y + grd.y; v = fmaf(a6.y, t, v); v = fmaf(a4.y, fabsf(t), v);
      t = g.z + grd.z; v = fmaf(a6.z, t, v); v = fmaf(a4.z, fabsf(t), v);
      t = g.w + grd.w; v = fmaf(a6.w, t, v); v = fmaf(a4.w, fabsf(t), v);
      v += __shfl_xor(v, 1); v += __shfl_xor(v, 2); v += __shfl_xor(v, 4);
      float ex = pv0 ? exp2f(v) : 0.f;
      denom += ex;
      A.x = fmaf(ex, g.x, A.x); A.y = fmaf(ex, g.y, A.y);
      A.z = fmaf(ex, g.z, A.z); A.w = fmaf(ex, g.w, A.w);
      u0 = u1; pv0 = pv1;
      u1 = un; pv1 = pvn;
    }
  }
  denom += __shfl_xor(denom, 8); denom += __shfl_xor(denom, 16); denom += __shfl_xor(denom, 32);
  A.x += __shfl_xor(A.x, 8); A.x += __shfl_xor(A.x, 16); A.x += __shfl_xor(A.x, 32);
  A.y += __shfl_xor(A.y, 8); A.y += __shfl_xor(A.y, 16); A.y += __shfl_xor(A.y, 32);
  A.z += __shfl_xor(A.z, 8); A.z += __shfl_xor(A.z, 16); A.z += __shfl_xor(A.z, 32);
  A.w += __shfl_xor(A.w, 8); A.w += __shfl_xor(A.w, 16); A.w += __shfl_xor(A.w, 32);
  if (eslot == 0) {
    float inv = __builtin_amdgcn_rcpf(denom);
    float4 bv = *(const float4*)(bias + c4);
    float4 o;
    o.x = A.x * inv + bv.x; o.y = A.y * inv + bv.y;
    o.z = A.z * inv + bv.z; o.w = A.w * inv + bv.w;
    *(float4*)(out + (size_t)node * 32 + c4) = o;
  }
}

extern "C" void kernel_launch(void* const* d_in, const int* in_sizes, int n_in,
                              void* d_out, int out_size, void* d_ws, size_t ws_size,
                              hipStream_t stream) {
  const float* x     = (const float*)d_in[0];
  const int*   ei    = (const int*)  d_in[1];
  const float* Wl1   = (const float*)d_in[2];
  const float* bl1   = (const float*)d_in[3];
  const float* Wr1   = (const float*)d_in[4];
  const float* br1   = (const float*)d_in[5];
  const float* att1  = (const float*)d_in[6];
  const float* bias1 = (const float*)d_in[7];
  const float* Wl2   = (const float*)d_in[8];
  const float* bl2   = (const float*)d_in[9];
  const float* Wr2   = (const float*)d_in[10];
  const float* br2   = (const float*)d_in[11];
  const float* att2  = (const float*)d_in[12];
  const float* bias2 = (const float*)d_in[13];
  float* out = (float*)d_out;

  char* w = (char*)d_ws;
  auto carve = [&](size_t bytes) {
    char* p = w;
    w += (bytes + 255) & ~(size_t)255;
    return p;
  };
  ushort_t* gl1 = (ushort_t*)carve((size_t)NNODES * 128 * 2);   // bf16 gather table
  ushort_t* gr1 = (ushort_t*)carve((size_t)NNODES * 128 * 2);   // bf16
  ushort_t* h   = (ushort_t*)carve((size_t)NNODES * 128 * 2);   // bf16
  ushort_t* gl2 = (ushort_t*)carve((size_t)NNODES * 32 * 2);    // bf16 (fits XCD L2)
  ushort_t* gr2 = (ushort_t*)carve((size_t)NNODES * 32 * 2);    // bf16
  ushort_t* WtHi = (ushort_t*)carve((size_t)256 * 128 * 2);
  ushort_t* WtLo = (ushort_t*)carve((size_t)256 * 128 * 2);
  ushort_t* Wt2Hi = (ushort_t*)carve((size_t)64 * 128 * 2);
  ushort_t* Wt2Lo = (ushort_t*)carve((size_t)64 * 128 * 2);
  int* pcnt    = (int*)carve((size_t)NP1 * BKTS * 4);
  int* goffArr = (int*)carve((size_t)NP1 * BKTS * 4);
  int* tot     = (int*)carve((size_t)BKTS * 4);
  int* bucketStart = (int*)carve((size_t)(BKTS + 1) * 4);
  int* rowptr = (int*)carve((size_t)(NNODES + 1) * 4);
  uint_t* binned = (uint_t*)carve((size_t)ETOT * 4);
  int* csrc = (int*)carve((size_t)ETOT * 4);
  int* done = (int*)carve(4);

  // CSR pipeline and GEMM1 pipeline are independent until gat1; overlap them.
  fusedA<<<NP1 + 128 + 32, 256, 0, stream>>>(ei, pcnt, Wl1, Wr1, WtHi, WtLo,
                                             Wl2, Wr2, Wt2Hi, Wt2Lo, done);
  coarse_scan<<<BKTS, 64, 0, stream>>>(pcnt, goffArr, tot, bucketStart, rowptr, done);
  fusedB<<<NP1 + GEMM1_H1, 256, 0, stream>>>(ei, bucketStart, goffArr, binned,
                                             x, WtHi, WtLo, bl1, br1, gl1, gr1);
  fusedC<<<BKTS + GEMM1_H2, 256, 0, stream>>>(binned, bucketStart, rowptr, csrc,
                                              x, WtHi, WtLo, bl1, br1, gl1, gr1);
  gat1_edge<<<(NNODES + 1) / 2, 128, 0, stream>>>(rowptr, csrc, gl1, gr1, att1, bias1, h);
  gemm2_mfma<<<GEMM1_NB, 256, 0, stream>>>(h, Wt2Hi, Wt2Lo, bl2, br2, gl2, gr2);
  gat2_edge<<<(NNODES + 1) / 2, 128, 0, stream>>>(rowptr, csrc, gl2, gr2, att2, bias2, out);
}